// Round 2
// baseline (447.654 us; speedup 1.0000x reference)
//
#include <hip/hip_runtime.h>

// ---------------------------------------------------------------------------
// Math insight: hidden0 = zeros((T,H)) and the scan step applies the SAME
// row-wise update to every row, so all T rows of the carry remain identical.
// The whole computation reduces to ONE H-dim vector recurrence:
//     h_{t+1} = tanh(x_t @ W_ih + h_t @ W_hh),   h_0 = 0
// output = (h_T @ fc_W + fc_b) broadcast to all T rows.
//
// Cost model: the recurrence is strictly serial in t (tanh => no scan trick),
// each step is a 256x256 matvec = 65536 MACs. One workgroup (1 CU) is optimal
// (cross-CU sync per step costs more than the compute it saves). Floor:
// 65536/128 MAC-lanes = 512 cyc/step (=~109us) scalar, ~half if pk_fma is
// dual-rate. Everything else (V GEMM, fc, broadcast) is parallel and tiny.
// ---------------------------------------------------------------------------

#define T_LEN 512
#define H_DIM 256

typedef float f32x2 __attribute__((ext_vector_type(2)));
typedef float f32x4 __attribute__((ext_vector_type(4)));

__device__ __forceinline__ f32x2 pk_fma(f32x2 a, f32x2 b, f32x2 c) {
    f32x2 d;
    asm("v_pk_fma_f32 %0, %1, %2, %3" : "=v"(d) : "v"(a), "v"(b), "v"(c));
    return d;
}

__device__ __forceinline__ float fast_rcp(float x) {
    return __builtin_amdgcn_rcpf(x);   // v_rcp_f32, ~1e-7 rel err
}

// ---------------------------------------------------------------------------
// Kernel A: V = x @ W_ih   (T x H). V aliases d_out (used as scratch).
// grid = T/4 = 128 blocks x 256 threads; thread j computes 4 rows' column j.
// ---------------------------------------------------------------------------
__global__ __launch_bounds__(256) void vih_kernel(const float* __restrict__ x,
                                                  const float* __restrict__ W_ih,
                                                  float* __restrict__ V) {
    const int j  = threadIdx.x;
    const int t0 = blockIdx.x * 4;
    __shared__ float xs[4][H_DIM];
#pragma unroll
    for (int r = 0; r < 4; ++r) xs[r][j] = x[(t0 + r) * H_DIM + j];
    __syncthreads();
    float a0 = 0.f, a1 = 0.f, a2 = 0.f, a3 = 0.f;
#pragma unroll 8
    for (int i = 0; i < H_DIM; ++i) {
        float wv = W_ih[i * H_DIM + j];      // coalesced; xs[.][i] broadcasts
        a0 = fmaf(xs[0][i], wv, a0);
        a1 = fmaf(xs[1][i], wv, a1);
        a2 = fmaf(xs[2][i], wv, a2);
        a3 = fmaf(xs[3][i], wv, a3);
    }
    V[(t0 + 0) * H_DIM + j] = a0;
    V[(t0 + 1) * H_DIM + j] = a1;
    V[(t0 + 2) * H_DIM + j] = a2;
    V[(t0 + 3) * H_DIM + j] = a3;
}

// ---------------------------------------------------------------------------
// Kernel B: the sequential recurrence on ONE workgroup (1024 threads).
//   thread (j = tid>>2, g = tid&3): owns W_hh[g*64 .. g*64+63][j] in 64 VGPRs.
//   h in LDS, padded (68 floats per 64-slice) so the 4 g-groups' ds_read_b128
//   hit disjoint banks. Quad shfl_xor reduce (DPP). Double-buffered h => ONE
//   barrier/step; raw s_barrier + lgkmcnt(0) only: the lgkmcnt(0) drains BOTH
//   this lane's reads of the old buffer (so the next write to it is safe) AND
//   the writer's ds_write (so readers see h_new) — while global prefetch of V
//   (2 steps ahead) survives the barrier (no vmcnt(0) drain).
// Tail: y = h_T @ fc_W + fc_b  ->  d_ws (1 KB). Broadcast is kernel C.
// NOTE: V aliases d_out (no __restrict__ on V here, deliberately).
// ---------------------------------------------------------------------------
__global__ __launch_bounds__(1024) void rnn_scan_kernel(
        const float* __restrict__ W_hh,
        const float* V,
        const float* __restrict__ fc_W,
        const float* __restrict__ fc_b,
        float* __restrict__ y_out) {
    const int tid  = threadIdx.x;
    const int j    = tid >> 2;   // output column 0..255
    const int g    = tid & 3;    // row-group 0..3 (rows g*64 .. g*64+63)
    const int goff = g * 17;     // padded float4 offset of this group's h slice

    // ---- W_hh fragment into registers: w2[k2] = W_hh[g*64+2k2(+1)][j]
    f32x2 w2[32];
    {
        const float* wp = W_hh + (g * 64) * H_DIM + j;
#pragma unroll
        for (int k2 = 0; k2 < 32; ++k2) {
            w2[k2].x = wp[(2 * k2) * H_DIM];
            w2[k2].y = wp[(2 * k2 + 1) * H_DIM];
        }
    }

    // padded h: logical h[i], i = 64*gb + k  ->  float index gb*68 + k
    __shared__ f32x4 h4p[2][68];
    {
        float* hz = (float*)h4p;
        for (int idx = tid; idx < 2 * 68 * 4; idx += 1024) hz[idx] = 0.f;
    }
    __syncthreads();

    float vA = V[0 * H_DIM + j];   // v_t for t=0
    float vB = V[1 * H_DIM + j];   // v_t for t=1

#define RNN_STEP(vt, RB, WB)                                                  \
  {                                                                           \
    const f32x4* hb = &h4p[RB][goff];                                         \
    f32x2 a0 = {0.f, 0.f}, a1 = {0.f, 0.f}, a2 = {0.f, 0.f}, a3 = {0.f, 0.f};\
    _Pragma("unroll")                                                         \
    for (int k16 = 0; k16 < 16; ++k16) {                                      \
      f32x4 hv = hb[k16];                   /* broadcast, conflict-free */    \
      f32x2 lo; lo.x = hv.x; lo.y = hv.y;                                     \
      f32x2 hi; hi.x = hv.z; hi.y = hv.w;                                     \
      if ((k16 & 1) == 0) {                                                   \
        a0 = pk_fma(w2[2 * k16], lo, a0);                                     \
        a1 = pk_fma(w2[2 * k16 + 1], hi, a1);                                 \
      } else {                                                                \
        a2 = pk_fma(w2[2 * k16], lo, a2);                                     \
        a3 = pk_fma(w2[2 * k16 + 1], hi, a3);                                 \
      }                                                                       \
    }                                                                         \
    float s = ((a0.x + a2.x) + (a0.y + a2.y)) +                               \
              ((a1.x + a3.x) + (a1.y + a3.y));                                \
    s += __shfl_xor(s, 1);                                                    \
    s += __shfl_xor(s, 2);                                                    \
    s += (vt);                                                                \
    float e_ = __expf(2.f * s);                                               \
    float hnew_ = 1.f - 2.f * fast_rcp(e_ + 1.f);  /* tanh(s) */              \
    if ((tid & 3) == 0)                                                       \
      ((float*)h4p[WB])[(j >> 6) * 68 + (j & 63)] = hnew_;                    \
    asm volatile("s_waitcnt lgkmcnt(0)" ::: "memory");                        \
    __builtin_amdgcn_s_barrier();                                             \
    asm volatile("" ::: "memory");                                            \
  }

    for (int t = 0; t < T_LEN; t += 2) {
        // prefetch v_{t+2}, v_{t+3}: consumed 2 / 1.5 steps later; the raw
        // barrier does NOT drain vmcnt, so these stay in flight under compute.
        float vA2 = V[(t + 2 < T_LEN ? t + 2 : T_LEN - 1) * H_DIM + j];
        float vB2 = V[(t + 3 < T_LEN ? t + 3 : T_LEN - 1) * H_DIM + j];
        RNN_STEP(vA, 0, 1);   // even step: read buf0 -> write buf1
        RNN_STEP(vB, 1, 0);   // odd  step: read buf1 -> write buf0
        vA = vA2;
        vB = vB2;
    }
    // T even => final h is in buffer 0.

    // ---- tail: y[j] = sum_i h[i] * fc_W[i][j] + fc_b[j]  -> y_out (d_ws)
    {
        const f32x4* hb = &h4p[0][goff];
        const float* fwp = fc_W + (g * 64) * H_DIM + j;
        f32x2 b0 = {0.f, 0.f}, b1 = {0.f, 0.f};
#pragma unroll 4
        for (int k16 = 0; k16 < 16; ++k16) {
            f32x4 hv = hb[k16];
            f32x2 lo; lo.x = hv.x; lo.y = hv.y;
            f32x2 hi; hi.x = hv.z; hi.y = hv.w;
            f32x2 f0; f0.x = fwp[(4 * k16) * H_DIM];     f0.y = fwp[(4 * k16 + 1) * H_DIM];
            f32x2 f1; f1.x = fwp[(4 * k16 + 2) * H_DIM]; f1.y = fwp[(4 * k16 + 3) * H_DIM];
            b0 = pk_fma(f0, lo, b0);
            b1 = pk_fma(f1, hi, b1);
        }
        float ys = (b0.x + b0.y) + (b1.x + b1.y);
        ys += __shfl_xor(ys, 1);
        ys += __shfl_xor(ys, 2);
        if ((tid & 3) == 0) y_out[j] = ys + fc_b[j];
    }
#undef RNN_STEP
}

// ---------------------------------------------------------------------------
// Kernel C: broadcast y (256 floats in d_ws) to all T rows of out. Runs on
// many CUs so the 512 KB of stores drain at chip write BW, not one CU's.
// ---------------------------------------------------------------------------
__global__ __launch_bounds__(256) void bcast_kernel(const float* __restrict__ y,
                                                    float* __restrict__ out) {
    __shared__ f32x4 yl[H_DIM / 4];
    if (threadIdx.x < H_DIM / 4) yl[threadIdx.x] = ((const f32x4*)y)[threadIdx.x];
    __syncthreads();
    // block b writes rows 4b..4b+3 (4 KB), thread idx -> one float4
    const int base = blockIdx.x * (4 * H_DIM / 4);
    f32x4* o4 = (f32x4*)out;
    o4[base + threadIdx.x] = yl[threadIdx.x & 63];
}

extern "C" void kernel_launch(void* const* d_in, const int* in_sizes, int n_in,
                              void* d_out, int out_size, void* d_ws, size_t ws_size,
                              hipStream_t stream) {
    (void)in_sizes; (void)n_in; (void)ws_size; (void)out_size;
    const float* x    = (const float*)d_in[0];
    const float* W_ih = (const float*)d_in[1];
    const float* W_hh = (const float*)d_in[2];
    const float* fc_W = (const float*)d_in[3];
    const float* fc_b = (const float*)d_in[4];
    float* out = (float*)d_out;
    float* y   = (float*)d_ws;          // 1 KB of the workspace

    // d_out (512*256 floats = 512 KB) doubles as scratch for V = x @ W_ih;
    // the recurrence kernel only reads V; kernel C overwrites d_out last.
    float* V = out;

    vih_kernel<<<T_LEN / 4, 256, 0, stream>>>(x, W_ih, V);
    rnn_scan_kernel<<<1, 1024, 0, stream>>>(W_hh, V, fc_W, fc_b, y);
    bcast_kernel<<<T_LEN / 4, 256, 0, stream>>>(y, out);
}

// Round 3
// 411.034 us; speedup vs baseline: 1.0891x; 1.0891x over previous
//
#include <hip/hip_runtime.h>

// ---------------------------------------------------------------------------
// Math insight: hidden0 = zeros((T,H)) and the scan step applies the SAME
// row-wise update to every row, so all T rows of the carry remain identical.
// The whole computation reduces to ONE H-dim vector recurrence:
//     h_{t+1} = tanh(x_t @ W_ih + h_t @ W_hh),   h_0 = 0
// output = (h_T @ fc_W + fc_b) broadcast to all T rows.
//
// R2 post-mortem: VGPR_Count=52 proved hipcc (launch_bounds(1024), no 2nd
// arg) capped regs for 2-blocks/CU occupancy and re-loaded W_hh from cache
// EVERY step (~1800 cyc/step). Fix: 512 threads + __launch_bounds__(512,2)
// -> 256-VGPR budget; 128 W_hh elements/thread pinned in registers.
// Floor: 65536 MAC/step / 128 fp32-FMA-lanes/CU = 512 cyc/step (~109us).
// ---------------------------------------------------------------------------

#define T_LEN 512
#define H_DIM 256

typedef float f32x2 __attribute__((ext_vector_type(2)));
typedef float f32x4 __attribute__((ext_vector_type(4)));

__device__ __forceinline__ f32x2 pk_fma(f32x2 a, f32x2 b, f32x2 c) {
    f32x2 d;
    asm("v_pk_fma_f32 %0, %1, %2, %3" : "=v"(d) : "v"(a), "v"(b), "v"(c));
    return d;
}

__device__ __forceinline__ float fast_rcp(float x) {
    return __builtin_amdgcn_rcpf(x);   // v_rcp_f32, ~1e-7 rel err
}

// xor-1 lane swap via DPP quad_perm(1,0,3,2): VALU-only, no LDS pipe use.
__device__ __forceinline__ float dpp_xor1(float s) {
    int r = __builtin_amdgcn_mov_dpp(__float_as_int(s), 0xB1, 0xF, 0xF, true);
    return __int_as_float(r);
}

// ---------------------------------------------------------------------------
// Kernel A: V = x @ W_ih   (T x H). V aliases d_out (used as scratch).
// grid = T/4 = 128 blocks x 256 threads; thread j computes 4 rows' column j.
// ---------------------------------------------------------------------------
__global__ __launch_bounds__(256) void vih_kernel(const float* __restrict__ x,
                                                  const float* __restrict__ W_ih,
                                                  float* __restrict__ V) {
    const int j  = threadIdx.x;
    const int t0 = blockIdx.x * 4;
    __shared__ float xs[4][H_DIM];
#pragma unroll
    for (int r = 0; r < 4; ++r) xs[r][j] = x[(t0 + r) * H_DIM + j];
    __syncthreads();
    float a0 = 0.f, a1 = 0.f, a2 = 0.f, a3 = 0.f;
#pragma unroll 8
    for (int i = 0; i < H_DIM; ++i) {
        float wv = W_ih[i * H_DIM + j];      // coalesced; xs[.][i] broadcasts
        a0 = fmaf(xs[0][i], wv, a0);
        a1 = fmaf(xs[1][i], wv, a1);
        a2 = fmaf(xs[2][i], wv, a2);
        a3 = fmaf(xs[3][i], wv, a3);
    }
    V[(t0 + 0) * H_DIM + j] = a0;
    V[(t0 + 1) * H_DIM + j] = a1;
    V[(t0 + 2) * H_DIM + j] = a2;
    V[(t0 + 3) * H_DIM + j] = a3;
}

// ---------------------------------------------------------------------------
// Kernel B: sequential recurrence, ONE workgroup, 512 threads, 2 waves/SIMD.
//   thread (j = tid>>1, g = tid&1): owns W_hh[g*128 .. g*128+127][j] in
//   128 VGPRs (64 x f32x2). h in LDS, group slice stride 33 float4 so the
//   two g-groups' ds_read_b128 hit disjoint banks. Pair reduce via DPP.
//   Double-buffered h => ONE barrier/step; raw s_barrier + lgkmcnt(0) only:
//   drains this lane's reads of the old buffer (next write safe) AND the
//   writer's ds_write (readers see h_new), while the global V prefetch
//   (2 steps ahead) survives the barrier (no vmcnt(0) drain).
// Tail: y = h_T @ fc_W + fc_b  ->  d_ws (1 KB). Broadcast is kernel C.
// NOTE: V aliases d_out (no __restrict__ on V here, deliberately).
// ---------------------------------------------------------------------------
__global__ __launch_bounds__(512, 2) void rnn_scan_kernel(
        const float* __restrict__ W_hh,
        const float* V,
        const float* __restrict__ fc_W,
        const float* __restrict__ fc_b,
        float* __restrict__ y_out) {
    const int tid  = threadIdx.x;
    const int j    = tid >> 1;   // output column 0..255
    const int g    = tid & 1;    // row-group 0/1 (rows g*128 .. g*128+127)
    const int goff = g * 33;     // padded float4 offset of this group's h slice

    // ---- W_hh fragment into registers: w2[k2] = W_hh[g*128+2k2(+1)][j]
    f32x2 w2[64];
    {
        const float* wp = W_hh + (g * 128) * H_DIM + j;
#pragma unroll
        for (int k2 = 0; k2 < 64; ++k2) {
            w2[k2].x = wp[(2 * k2) * H_DIM];
            w2[k2].y = wp[(2 * k2 + 1) * H_DIM];
        }
    }

    // padded h: logical h[i], i = 128*gb + k  ->  float index gb*132 + k
    __shared__ f32x4 h4p[2][66];
    {
        float* hz = (float*)h4p;
        for (int idx = tid; idx < 2 * 66 * 4; idx += 512) hz[idx] = 0.f;
    }
    __syncthreads();

    float vA = V[0 * H_DIM + j];   // v_t for t=0
    float vB = V[1 * H_DIM + j];   // v_t for t=1

#define RNN_STEP(vt, RB, WB)                                                  \
  {                                                                           \
    const f32x4* hb = &h4p[RB][goff];                                         \
    f32x2 a0 = {0.f, 0.f}, a1 = {0.f, 0.f}, a2 = {0.f, 0.f}, a3 = {0.f, 0.f};\
    _Pragma("unroll")                                                         \
    for (int k16 = 0; k16 < 32; ++k16) {                                      \
      f32x4 hv = hb[k16];           /* 2 addrs/wave, disjoint banks */        \
      f32x2 lo; lo.x = hv.x; lo.y = hv.y;                                     \
      f32x2 hi; hi.x = hv.z; hi.y = hv.w;                                     \
      if ((k16 & 1) == 0) {                                                   \
        a0 = pk_fma(w2[2 * k16], lo, a0);                                     \
        a1 = pk_fma(w2[2 * k16 + 1], hi, a1);                                 \
      } else {                                                                \
        a2 = pk_fma(w2[2 * k16], lo, a2);                                     \
        a3 = pk_fma(w2[2 * k16 + 1], hi, a3);                                 \
      }                                                                       \
    }                                                                         \
    float s = ((a0.x + a2.x) + (a0.y + a2.y)) +                               \
              ((a1.x + a3.x) + (a1.y + a3.y));                                \
    s += dpp_xor1(s);                                                         \
    s += (vt);                                                                \
    float e_ = __expf(2.f * s);                                               \
    float hnew_ = 1.f - 2.f * fast_rcp(e_ + 1.f);  /* tanh(s) */              \
    if ((tid & 1) == 0)                                                       \
      ((float*)h4p[WB])[(j >> 7) * 132 + (j & 127)] = hnew_;                  \
    asm volatile("s_waitcnt lgkmcnt(0)" ::: "memory");                        \
    __builtin_amdgcn_s_barrier();                                             \
    asm volatile("" ::: "memory");                                            \
  }

    for (int t = 0; t < T_LEN; t += 2) {
        // prefetch v_{t+2}, v_{t+3}: consumed 1.5-2 steps later; the raw
        // barrier does NOT drain vmcnt, so these stay in flight under compute.
        float vA2 = V[(t + 2 < T_LEN ? t + 2 : T_LEN - 1) * H_DIM + j];
        float vB2 = V[(t + 3 < T_LEN ? t + 3 : T_LEN - 1) * H_DIM + j];
        RNN_STEP(vA, 0, 1);   // even step: read buf0 -> write buf1
        RNN_STEP(vB, 1, 0);   // odd  step: read buf1 -> write buf0
        vA = vA2;
        vB = vB2;
    }
    // T even => final h is in buffer 0.

    // ---- tail: y[j] = sum_i h[i] * fc_W[i][j] + fc_b[j]  -> y_out (d_ws)
    {
        const f32x4* hb = &h4p[0][goff];
        const float* fwp = fc_W + (g * 128) * H_DIM + j;
        f32x2 b0 = {0.f, 0.f}, b1 = {0.f, 0.f};
#pragma unroll 8
        for (int k16 = 0; k16 < 32; ++k16) {
            f32x4 hv = hb[k16];
            f32x2 lo; lo.x = hv.x; lo.y = hv.y;
            f32x2 hi; hi.x = hv.z; hi.y = hv.w;
            f32x2 f0; f0.x = fwp[(4 * k16) * H_DIM];     f0.y = fwp[(4 * k16 + 1) * H_DIM];
            f32x2 f1; f1.x = fwp[(4 * k16 + 2) * H_DIM]; f1.y = fwp[(4 * k16 + 3) * H_DIM];
            b0 = pk_fma(f0, lo, b0);
            b1 = pk_fma(f1, hi, b1);
        }
        float ys = (b0.x + b0.y) + (b1.x + b1.y);
        ys += dpp_xor1(ys);
        if ((tid & 1) == 0) y_out[j] = ys + fc_b[j];
    }
#undef RNN_STEP
}

// ---------------------------------------------------------------------------
// Kernel C: broadcast y (256 floats in d_ws) to all T rows of out. Runs on
// many CUs so the 512 KB of stores drain at chip write BW, not one CU's.
// ---------------------------------------------------------------------------
__global__ __launch_bounds__(256) void bcast_kernel(const float* __restrict__ y,
                                                    float* __restrict__ out) {
    __shared__ f32x4 yl[H_DIM / 4];
    if (threadIdx.x < H_DIM / 4) yl[threadIdx.x] = ((const f32x4*)y)[threadIdx.x];
    __syncthreads();
    // block b writes rows 4b..4b+3 (4 KB), thread idx -> one float4
    const int base = blockIdx.x * (4 * H_DIM / 4);
    f32x4* o4 = (f32x4*)out;
    o4[base + threadIdx.x] = yl[threadIdx.x & 63];
}

extern "C" void kernel_launch(void* const* d_in, const int* in_sizes, int n_in,
                              void* d_out, int out_size, void* d_ws, size_t ws_size,
                              hipStream_t stream) {
    (void)in_sizes; (void)n_in; (void)ws_size; (void)out_size;
    const float* x    = (const float*)d_in[0];
    const float* W_ih = (const float*)d_in[1];
    const float* W_hh = (const float*)d_in[2];
    const float* fc_W = (const float*)d_in[3];
    const float* fc_b = (const float*)d_in[4];
    float* out = (float*)d_out;
    float* y   = (float*)d_ws;          // 1 KB of the workspace

    // d_out (512*256 floats = 512 KB) doubles as scratch for V = x @ W_ih;
    // the recurrence kernel only reads V; kernel C overwrites d_out last.
    float* V = out;

    vih_kernel<<<T_LEN / 4, 256, 0, stream>>>(x, W_ih, V);
    rnn_scan_kernel<<<1, 512, 0, stream>>>(W_hh, V, fc_W, fc_b, y);
    bcast_kernel<<<T_LEN / 4, 256, 0, stream>>>(y, out);
}

// Round 4
// 352.331 us; speedup vs baseline: 1.2706x; 1.1666x over previous
//
#include <hip/hip_runtime.h>

// ---------------------------------------------------------------------------
// Math insight: hidden0 = zeros((T,H)) and the scan step applies the SAME
// row-wise update to every row, so all T rows of the carry remain identical.
// Everything reduces to ONE 256-dim vector recurrence:
//     h_{t+1} = tanh(x_t @ W_ih + h_t @ W_hh),   h_0 = 0
// output = (h_T @ fc_W + fc_b) broadcast to all T rows.
//
// R3 post-mortem: VGPR_Count=80 (twice) => W_hh fragment spilled to scratch,
// reloaded every step (~1650 cyc/step). Cause hypothesis: launch_bounds 2nd
// arg behaves as min-BLOCKS/CU -> effective VGPR cap 128 < ~170 needed.
// Fix: amdgpu_waves_per_eu(2,2) pins 2 waves/SIMD -> hard cap 256 VGPRs.
// Also: C=2 columns/thread halves LDS instr pressure; quad DPP butterfly.
// Gate for this round: VGPR_Count must read ~180; else allocation failed.
// ---------------------------------------------------------------------------

#define T_LEN 512
#define H_DIM 256

typedef float f32x2 __attribute__((ext_vector_type(2)));
typedef float f32x4 __attribute__((ext_vector_type(4)));

__device__ __forceinline__ f32x2 pk_fma(f32x2 a, f32x2 b, f32x2 c) {
    f32x2 d;
    asm("v_pk_fma_f32 %0, %1, %2, %3" : "=v"(d) : "v"(a), "v"(b), "v"(c));
    return d;
}
__device__ __forceinline__ float fast_rcp(float x) {
    return __builtin_amdgcn_rcpf(x);   // v_rcp_f32, ~1e-7 rel err
}
// quad_perm DPP lane swaps: VALU-only (no LDS pipe), all lanes active.
__device__ __forceinline__ float dpp_xor1(float s) {
    return __int_as_float(__builtin_amdgcn_mov_dpp(__float_as_int(s), 0xB1, 0xF, 0xF, true));
}
__device__ __forceinline__ float dpp_xor2(float s) {
    return __int_as_float(__builtin_amdgcn_mov_dpp(__float_as_int(s), 0x4E, 0xF, 0xF, true));
}
__device__ __forceinline__ float tanh_fast(float x) {
    float e = __expf(x + x);
    return 1.f - 2.f * fast_rcp(e + 1.f);
}

// ---------------------------------------------------------------------------
// Kernel A: V = x @ W_ih   (T x H). V aliases d_out (used as scratch).
// ---------------------------------------------------------------------------
__global__ __launch_bounds__(256) void vih_kernel(const float* __restrict__ x,
                                                  const float* __restrict__ W_ih,
                                                  float* __restrict__ V) {
    const int j  = threadIdx.x;
    const int t0 = blockIdx.x * 4;
    __shared__ float xs[4][H_DIM];
#pragma unroll
    for (int r = 0; r < 4; ++r) xs[r][j] = x[(t0 + r) * H_DIM + j];
    __syncthreads();
    float a0 = 0.f, a1 = 0.f, a2 = 0.f, a3 = 0.f;
#pragma unroll 8
    for (int i = 0; i < H_DIM; ++i) {
        float wv = W_ih[i * H_DIM + j];      // coalesced; xs[.][i] broadcasts
        a0 = fmaf(xs[0][i], wv, a0);
        a1 = fmaf(xs[1][i], wv, a1);
        a2 = fmaf(xs[2][i], wv, a2);
        a3 = fmaf(xs[3][i], wv, a3);
    }
    V[(t0 + 0) * H_DIM + j] = a0;
    V[(t0 + 1) * H_DIM + j] = a1;
    V[(t0 + 2) * H_DIM + j] = a2;
    V[(t0 + 3) * H_DIM + j] = a3;
}

// ---------------------------------------------------------------------------
// Kernel B: sequential recurrence, ONE workgroup, 512 threads, 2 waves/SIMD
// (pinned via amdgpu_waves_per_eu(2,2) -> 256-VGPR budget).
// Thread (j2 = tid>>2, g = tid&3): columns {2j2, 2j2+1}, rows g*64..g*64+63.
// 128 W_hh elements/thread in VGPRs (wA/wB, 64 x f32x2). Each LDS h-read
// feeds 2 columns (halved LDS pressure). h slices padded to 17 float4 so the
// 4 g-groups' ds_read_b128 hit disjoint bank quads (16-lane broadcast each).
// Quad reduce = 2 DPP steps. One ds_write_b64 per column pair. One raw
// s_barrier/step with lgkmcnt(0) only (V prefetch survives; no vmcnt drain).
// ---------------------------------------------------------------------------
__global__ __attribute__((amdgpu_waves_per_eu(2, 2))) __launch_bounds__(512)
void rnn_scan_kernel(const float* __restrict__ W_hh,
                     const float* V,
                     const float* __restrict__ fc_W,
                     const float* __restrict__ fc_b,
                     float* __restrict__ y_out) {
    const int tid = threadIdx.x;
    const int j2  = tid >> 2;          // column pair 0..127
    const int g   = tid & 3;           // row slice 0..3 (rows g*64 .. g*64+63)
    const int c0  = 2 * j2;

    // ---- W_hh fragment: wA/wB[i] = rows (g*64+2i, g*64+2i+1), cols c0 / c0+1
    f32x2 wA[32], wB[32];
    {
        const float* wp = W_hh + (g * 64) * H_DIM;
#pragma unroll
        for (int i = 0; i < 32; ++i) {
            wA[i].x = wp[(2 * i)     * H_DIM + c0];
            wA[i].y = wp[(2 * i + 1) * H_DIM + c0];
            wB[i].x = wp[(2 * i)     * H_DIM + c0 + 1];
            wB[i].y = wp[(2 * i + 1) * H_DIM + c0 + 1];
        }
    }

    // h: logical h[i] at float index (i>>6)*68 + (i&63); slice = 17 float4.
    __shared__ f32x4 h4p[2][68];
    {
        float* hz = (float*)h4p;
        for (int idx = tid; idx < 2 * 68 * 4; idx += 512) hz[idx] = 0.f;
    }
    __syncthreads();

    const f32x2* Vp = (const f32x2*)V;       // V[t][c0] = Vp[t*128 + j2]
    f32x2 vA = Vp[0 * 128 + j2];
    f32x2 vB = Vp[1 * 128 + j2];

#define RNN_STEP(vt, RB, WB)                                                   \
  {                                                                            \
    const f32x4* hb = &h4p[RB][g * 17];                                        \
    f32x2 aA0 = {0.f,0.f}, aA1 = {0.f,0.f}, aA2 = {0.f,0.f}, aA3 = {0.f,0.f}; \
    f32x2 aB0 = {0.f,0.f}, aB1 = {0.f,0.f}, aB2 = {0.f,0.f}, aB3 = {0.f,0.f}; \
    _Pragma("unroll")                                                          \
    for (int k = 0; k < 16; ++k) {                                             \
      f32x4 hv = hb[k];            /* 4 bank-quad-disjoint broadcasts/wave */  \
      f32x2 p0; p0.x = hv.x; p0.y = hv.y;                                      \
      f32x2 p1; p1.x = hv.z; p1.y = hv.w;                                      \
      if (k & 1) {                                                             \
        aA2 = pk_fma(wA[2 * k], p0, aA2); aA3 = pk_fma(wA[2 * k + 1], p1, aA3);\
        aB2 = pk_fma(wB[2 * k], p0, aB2); aB3 = pk_fma(wB[2 * k + 1], p1, aB3);\
      } else {                                                                 \
        aA0 = pk_fma(wA[2 * k], p0, aA0); aA1 = pk_fma(wA[2 * k + 1], p1, aA1);\
        aB0 = pk_fma(wB[2 * k], p0, aB0); aB1 = pk_fma(wB[2 * k + 1], p1, aB1);\
      }                                                                        \
    }                                                                          \
    f32x2 cA = (aA0 + aA2) + (aA1 + aA3);                                      \
    f32x2 cB = (aB0 + aB2) + (aB1 + aB3);                                      \
    float sA = cA.x + cA.y;                                                    \
    float sB = cB.x + cB.y;                                                    \
    sA += dpp_xor1(sA); sB += dpp_xor1(sB);                                    \
    sA += dpp_xor2(sA); sB += dpp_xor2(sB);   /* quad total */                 \
    f32x2 hn;                                                                  \
    hn.x = tanh_fast(sA + (vt).x);            /* V added ONCE, post-reduce */  \
    hn.y = tanh_fast(sB + (vt).y);                                             \
    if (g == 0)                                                                \
      *(f32x2*)((float*)h4p[WB] + ((c0 >> 6) * 68 + (c0 & 63))) = hn;          \
    asm volatile("s_waitcnt lgkmcnt(0)" ::: "memory");                         \
    __builtin_amdgcn_s_barrier();                                              \
    asm volatile("" ::: "memory");                                             \
  }

    for (int t = 0; t < T_LEN; t += 2) {
        // prefetch v_{t+2}, v_{t+3}: the raw barrier does NOT drain vmcnt,
        // so these stay in flight under the next step's compute.
        f32x2 vA2 = Vp[(t + 2 < T_LEN ? t + 2 : T_LEN - 1) * 128 + j2];
        f32x2 vB2 = Vp[(t + 3 < T_LEN ? t + 3 : T_LEN - 1) * 128 + j2];
        RNN_STEP(vA, 0, 1);   // even step: read buf0 -> write buf1
        RNN_STEP(vB, 1, 0);   // odd  step: read buf1 -> write buf0
        vA = vA2;
        vB = vB2;
    }
    // T even => final h is in buffer 0.

    // ---- tail: y[c] = sum_i h[i] * fc_W[i][c] + fc_b[c]  -> y_out (d_ws)
    {
        const f32x4* hb = &h4p[0][g * 17];
        const float* fp = fc_W + (g * 64) * H_DIM;
        f32x2 bA0 = {0.f,0.f}, bA1 = {0.f,0.f};
        f32x2 bB0 = {0.f,0.f}, bB1 = {0.f,0.f};
#pragma unroll
        for (int k = 0; k < 16; ++k) {
            f32x4 hv = hb[k];
            f32x2 p0; p0.x = hv.x; p0.y = hv.y;
            f32x2 p1; p1.x = hv.z; p1.y = hv.w;
            f32x2 fA0; fA0.x = fp[(4*k)*H_DIM + c0];     fA0.y = fp[(4*k+1)*H_DIM + c0];
            f32x2 fA1; fA1.x = fp[(4*k+2)*H_DIM + c0];   fA1.y = fp[(4*k+3)*H_DIM + c0];
            f32x2 fB0; fB0.x = fp[(4*k)*H_DIM + c0+1];   fB0.y = fp[(4*k+1)*H_DIM + c0+1];
            f32x2 fB1; fB1.x = fp[(4*k+2)*H_DIM + c0+1]; fB1.y = fp[(4*k+3)*H_DIM + c0+1];
            bA0 = pk_fma(fA0, p0, bA0); bA1 = pk_fma(fA1, p1, bA1);
            bB0 = pk_fma(fB0, p0, bB0); bB1 = pk_fma(fB1, p1, bB1);
        }
        f32x2 cA = bA0 + bA1;
        f32x2 cB = bB0 + bB1;
        float sA = cA.x + cA.y;
        float sB = cB.x + cB.y;
        sA += dpp_xor1(sA); sB += dpp_xor1(sB);
        sA += dpp_xor2(sA); sB += dpp_xor2(sB);
        if (g == 0) {
            f32x2 yb = ((const f32x2*)fc_b)[j2];
            f32x2 yv; yv.x = sA + yb.x; yv.y = sB + yb.y;
            ((f32x2*)y_out)[j2] = yv;
        }
    }
#undef RNN_STEP
}

// ---------------------------------------------------------------------------
// Kernel C: broadcast y (256 floats in d_ws) to all T rows of out (many CUs).
// ---------------------------------------------------------------------------
__global__ __launch_bounds__(256) void bcast_kernel(const float* __restrict__ y,
                                                    float* __restrict__ out) {
    __shared__ f32x4 yl[H_DIM / 4];
    if (threadIdx.x < H_DIM / 4) yl[threadIdx.x] = ((const f32x4*)y)[threadIdx.x];
    __syncthreads();
    const int base = blockIdx.x * (4 * H_DIM / 4);
    f32x4* o4 = (f32x4*)out;
    o4[base + threadIdx.x] = yl[threadIdx.x & 63];
}

extern "C" void kernel_launch(void* const* d_in, const int* in_sizes, int n_in,
                              void* d_out, int out_size, void* d_ws, size_t ws_size,
                              hipStream_t stream) {
    (void)in_sizes; (void)n_in; (void)ws_size; (void)out_size;
    const float* x    = (const float*)d_in[0];
    const float* W_ih = (const float*)d_in[1];
    const float* W_hh = (const float*)d_in[2];
    const float* fc_W = (const float*)d_in[3];
    const float* fc_b = (const float*)d_in[4];
    float* out = (float*)d_out;
    float* y   = (float*)d_ws;          // 1 KB of the workspace

    // d_out (512*256 floats = 512 KB) doubles as scratch for V = x @ W_ih;
    // the recurrence kernel only reads V; kernel C overwrites d_out last.
    float* V = out;

    vih_kernel<<<T_LEN / 4, 256, 0, stream>>>(x, W_ih, V);
    rnn_scan_kernel<<<1, 512, 0, stream>>>(W_hh, V, fc_W, fc_b, y);
    bcast_kernel<<<T_LEN / 4, 256, 0, stream>>>(y, out);
}